// Round 3
// baseline (63.903 us; speedup 1.0000x reference)
//
#include <hip/hip_runtime.h>
#include <math.h>

#define D 128
#define G 256

// ws layout:
//   [0,      512)   u  (128 f32)  = Wp @ We[0:G]
//   [512,    516)   c  (scalar)   = bp . We[0:G]
//   [1024,   1024 + 4*B)   s[B]   per-graph gated sums
//   [65536,  65536 + 4*N)  pv[N]  per-node dot with we2 (= We[G:G+D])

// One wave (64 lanes) per block.
//   block b in [0,128)  : u[b] = Wp[b,:] . We[0:256]
//   block b == 128      : c = bp . We[0:256]
//   block b >= 129      : zero s (float4 stores)
__global__ void prep_kernel(const float* __restrict__ Wp,
                            const float* __restrict__ bp,
                            const float* __restrict__ We,
                            float* __restrict__ u,
                            float* __restrict__ c,
                            float* __restrict__ s,
                            int B) {
    int b  = blockIdx.x;
    int li = threadIdx.x;   // 0..63

    if (b >= 129) {
        int idx4 = (b - 129) * 64 + li;          // float4 index into s
        if (idx4 * 4 + 3 < B) ((float4*)s)[idx4] = make_float4(0.f, 0.f, 0.f, 0.f);
        else {
            for (int j = idx4 * 4; j < B; ++j) s[j] = 0.f;   // tail (no-op when B%4==0)
        }
        return;
    }

    const float* row = (b < D) ? (Wp + (size_t)b * G) : bp;
    float4 rv = ((const float4*)row)[li];
    float4 wv = ((const float4*)We)[li];
    float p = rv.x * wv.x + rv.y * wv.y + rv.z * wv.z + rv.w * wv.w;
    #pragma unroll
    for (int m = 32; m >= 1; m >>= 1) p += __shfl_xor(p, m, 64);
    if (li == 0) {
        if (b < D) u[b] = p;
        else       *c  = p;
    }
}

// One 32-lane half-wave processes one node row (128 f32 = 32 x float4).
// Each wave owns a contiguous chunk of rows; seg_ids is sorted, so we keep a
// running (segment, acc) in the leader lane and flush one atomicAdd per
// segment change. The we2 dot (needed for the per-graph last-node term)
// rides along on the same streaming read and is written to pv[row].
__global__ void node_kernel(const float* __restrict__ hv,
                            const float* __restrict__ Wg,
                            const float* __restrict__ bg,
                            const int*   __restrict__ seg_ids,
                            const float* __restrict__ u,
                            const float* __restrict__ cptr,
                            const float* __restrict__ We,
                            float*       __restrict__ s,
                            float*       __restrict__ pv,
                            int N, int chunk) {
    int tid  = blockIdx.x * blockDim.x + threadIdx.x;
    int wave = tid >> 6;
    int lane = threadIdx.x & 63;
    int half = lane >> 5;   // which row of the pair
    int li   = lane & 31;   // lane within half

    int start = wave * chunk;
    if (start >= N) return;
    int end = min(start + chunk, N);

    const float4* hv4 = (const float4*)hv;
    float4 wg4 = ((const float4*)Wg)[li];        // constant per lane, hoisted
    float4 u4  = ((const float4*)u)[li];
    float4 w24 = ((const float4*)We)[64 + li];   // we2 = We[256:384]
    float  bgv = *bg;
    float  cv  = *cptr;

    int   cur = -1;
    float acc = 0.f;

    for (int r0 = start; r0 < end; r0 += 2) {
        int row = r0 + half;
        float val = 0.f;
        int   seg = -1;
        if (row < end) {
            float4 v = hv4[(size_t)row * 32 + li];
            float p1 = v.x * wg4.x + v.y * wg4.y + v.z * wg4.z + v.w * wg4.w;
            float p2 = v.x * u4.x  + v.y * u4.y  + v.z * u4.z  + v.w * u4.w;
            float p3 = v.x * w24.x + v.y * w24.y + v.z * w24.z + v.w * w24.w;
            // reduce within the 32-lane half (xor masks <=16 stay in-half)
            #pragma unroll
            for (int m = 16; m >= 1; m >>= 1) {
                p1 += __shfl_xor(p1, m, 64);
                p2 += __shfl_xor(p2, m, 64);
                p3 += __shfl_xor(p3, m, 64);
            }
            float gate = 1.f / (1.f + __expf(-(p1 + bgv)));
            val = gate * (p2 + cv);
            seg = seg_ids[row];   // broadcast load, uniform across half
            if (li == 0) pv[row] = p3;
        }
        if (li == 0 && seg >= 0) {
            if (seg != cur) {
                if (cur >= 0) atomicAdd(&s[cur], acc);
                cur = seg;
                acc = val;
            } else {
                acc += val;
            }
        }
    }
    if (li == 0 && cur >= 0) atomicAdd(&s[cur], acc);
}

// One thread per graph: logit = s[g] + pv[last_idx[g]] + be, then stable
// log-sigmoid + action select.
__global__ void final_kernel(const float* __restrict__ s,
                             const float* __restrict__ pv,
                             const float* __restrict__ be,
                             const int*   __restrict__ last_idx,
                             const int*   __restrict__ a,
                             float*       __restrict__ out,
                             int B) {
    int g = blockIdx.x * blockDim.x + threadIdx.x;
    if (g >= B) return;
    float logit = s[g] + pv[last_idx[g]] + *be;
    float x = (a[g] != 0) ? logit : -logit;       // log_probs[:, a]
    // log_sigmoid(x) = min(x,0) - log1p(exp(-|x|))
    out[g] = fminf(x, 0.f) - log1pf(__expf(-fabsf(x)));
}

extern "C" void kernel_launch(void* const* d_in, const int* in_sizes, int n_in,
                              void* d_out, int out_size, void* d_ws, size_t ws_size,
                              hipStream_t stream) {
    const float* hv       = (const float*)d_in[0];
    const float* Wg       = (const float*)d_in[1];
    const float* bg       = (const float*)d_in[2];
    const float* Wp       = (const float*)d_in[3];
    const float* bp       = (const float*)d_in[4];
    const float* We       = (const float*)d_in[5];
    const float* be       = (const float*)d_in[6];
    const int*   seg_ids  = (const int*)d_in[7];
    const int*   last_idx = (const int*)d_in[8];
    const int*   a        = (const int*)d_in[9];
    float*       out      = (float*)d_out;

    int N = in_sizes[0] / D;
    int B = in_sizes[8];

    float* u  = (float*)d_ws;
    float* c  = (float*)((char*)d_ws + 512);
    float* s  = (float*)((char*)d_ws + 1024);
    float* pv = (float*)((char*)d_ws + 65536);

    // prep: 129 compute blocks + zero-s blocks (64 float4 per block)
    int nzero = (B / 4 + 63) / 64;
    prep_kernel<<<129 + nzero, 64, 0, stream>>>(Wp, bp, We, u, c, s, B);

    const int nblocks = 2048;                 // 8192 waves, 32 waves/CU
    int waves = nblocks * 256 / 64;
    int chunk = (N + waves - 1) / waves;
    chunk = (chunk + 1) & ~1;                 // even so both halves stay in-chunk
    node_kernel<<<nblocks, 256, 0, stream>>>(hv, Wg, bg, seg_ids, u, c, We, s, pv, N, chunk);

    int fblocks = (B + 255) / 256;
    final_kernel<<<fblocks, 256, 0, stream>>>(s, pv, be, last_idx, a, out, B);
}

// Round 5
// 50.352 us; speedup vs baseline: 1.2691x; 1.2691x over previous
//
#include <hip/hip_runtime.h>
#include <math.h>

#define D 128
#define G 256

// ws layout:
//   [0,      512)           u  (128 f32) = Wp @ We[0:G]
//   [512,    516)           c  (scalar)  = bp . We[0:G]
//   [1024,   1024 + 4*B)    s[B]   per-graph gated sums
//   [65536,  65536 + 4*B)   pg[B]  hv[last_idx[g]] . we2

// DPP-based add of a permuted copy (VALU pipe, no LDS/DS traffic).
template <int CTRL>
__device__ __forceinline__ float dpp_add(float x) {
    int yi = __builtin_amdgcn_update_dpp(0, __float_as_int(x), CTRL, 0xf, 0xf, true);
    return x + __int_as_float(yi);
}

// Sum over each 16-lane row, result in every lane of the row.
// xor1 (quad_perm[1,0,3,2]=0xB1), xor2 (quad_perm[2,3,0,1]=0x4E),
// then rotate-by-4 (0x124) and rotate-by-8 (0x128) within the row.
__device__ __forceinline__ float row16_sum(float x) {
    x = dpp_add<0xB1>(x);
    x = dpp_add<0x4E>(x);
    x = dpp_add<0x124>(x);
    x = dpp_add<0x128>(x);
    return x;
}

// One 64-lane wave per block, role by blockIdx.x:
//   [0,128)              : u[b] = Wp[b,:] . We[0:256]
//   128                  : c = bp . We[0:256]
//   [129, 129+nzero)     : zero s (float4 stores)
//   [129+nzero, ...)     : gather pg[g] = hv[last_idx[g]] . we2  (2 graphs/block)
__global__ void prep_kernel(const float* __restrict__ Wp,
                            const float* __restrict__ bp,
                            const float* __restrict__ We,
                            const float* __restrict__ hv,
                            const int*   __restrict__ last_idx,
                            float* __restrict__ u,
                            float* __restrict__ c,
                            float* __restrict__ s,
                            float* __restrict__ pg,
                            int B, int nzero) {
    int b  = blockIdx.x;
    int lane = threadIdx.x;   // 0..63

    if (b < 129) {
        const float* row = (b < D) ? (Wp + (size_t)b * G) : bp;
        float4 rv = ((const float4*)row)[lane];
        float4 wv = ((const float4*)We)[lane];
        float p = rv.x * wv.x + rv.y * wv.y + rv.z * wv.z + rv.w * wv.w;
        #pragma unroll
        for (int m = 32; m >= 1; m >>= 1) p += __shfl_xor(p, m, 64);
        if (lane == 0) {
            if (b < D) u[b] = p;
            else       *c  = p;
        }
        return;
    }
    if (b < 129 + nzero) {
        int idx4 = (b - 129) * 64 + lane;        // float4 index into s
        if (idx4 * 4 + 3 < B) ((float4*)s)[idx4] = make_float4(0.f, 0.f, 0.f, 0.f);
        else {
            for (int j = idx4 * 4; j < B; ++j) s[j] = 0.f;  // tail (no-op if B%4==0)
        }
        return;
    }
    // gather: 2 graphs per block (one 32-lane half each)
    int g  = (b - 129 - nzero) * 2 + (lane >> 5);
    int li = lane & 31;
    if (g >= B) return;
    int row = last_idx[g];
    float4 v = ((const float4*)hv)[(size_t)row * 32 + li];
    float4 w = ((const float4*)We)[64 + li];     // we2 = We[256:384]
    float p = v.x * w.x + v.y * w.y + v.z * w.z + v.w * w.w;
    #pragma unroll
    for (int m = 16; m >= 1; m >>= 1) p += __shfl_xor(p, m, 64);
    if (li == 0) pg[g] = p;
}

// One 32-lane half-wave per node row (128 f32 = 32 x float4). Each wave owns
// a contiguous even-sized chunk; seg_ids is sorted, so the leader lane keeps
// a running (segment, acc) and flushes one atomicAdd per segment change.
// Reductions use DPP (VALU) for the in-row levels + one shfl_xor(16).
__global__ void node_kernel(const float* __restrict__ hv,
                            const float* __restrict__ Wg,
                            const float* __restrict__ bg,
                            const int*   __restrict__ seg_ids,
                            const float* __restrict__ u,
                            const float* __restrict__ cptr,
                            float*       __restrict__ s,
                            int N, int chunk) {
    int tid  = blockIdx.x * blockDim.x + threadIdx.x;
    int wave = tid >> 6;
    int lane = threadIdx.x & 63;
    int half = lane >> 5;   // which row of the pair
    int li   = lane & 31;   // lane within half

    int start = wave * chunk;
    if (start >= N) return;
    int end = min(start + chunk, N);   // start, end, N all even -> no tail branch

    const float4* hv4 = (const float4*)hv;
    float4 wg4 = ((const float4*)Wg)[li];   // constant per lane, hoisted
    float4 u4  = ((const float4*)u)[li];
    float  bgv = *bg;
    float  cv  = *cptr;

    int   cur = -1;
    float acc = 0.f;

    for (int r0 = start; r0 < end; r0 += 2) {
        int row = r0 + half;
        float4 v = hv4[(size_t)row * 32 + li];
        int   seg = seg_ids[row];            // broadcast load, uniform per half
        float p1 = v.x * wg4.x + v.y * wg4.y + v.z * wg4.z + v.w * wg4.w;
        float p2 = v.x * u4.x  + v.y * u4.y  + v.z * u4.z  + v.w * u4.w;
        p1 = row16_sum(p1);
        p2 = row16_sum(p2);
        p1 += __shfl_xor(p1, 16, 64);        // cross the two 16-rows of the half
        p2 += __shfl_xor(p2, 16, 64);
        float gate = 1.f / (1.f + __expf(-(p1 + bgv)));
        float val = gate * (p2 + cv);
        if (li == 0) {
            if (seg != cur) {
                if (cur >= 0) atomicAdd(&s[cur], acc);
                cur = seg;
                acc = val;
            } else {
                acc += val;
            }
        }
    }
    if (li == 0 && cur >= 0) atomicAdd(&s[cur], acc);
}

// One thread per graph: logit = s[g] + pg[g] + be, stable log-sigmoid + select.
__global__ void final_kernel(const float* __restrict__ s,
                             const float* __restrict__ pg,
                             const float* __restrict__ be,
                             const int*   __restrict__ a,
                             float*       __restrict__ out,
                             int B) {
    int g = blockIdx.x * blockDim.x + threadIdx.x;
    if (g >= B) return;
    float logit = s[g] + pg[g] + *be;
    float x = (a[g] != 0) ? logit : -logit;       // log_probs[:, a]
    // log_sigmoid(x) = min(x,0) - log1p(exp(-|x|))
    out[g] = fminf(x, 0.f) - log1pf(__expf(-fabsf(x)));
}

extern "C" void kernel_launch(void* const* d_in, const int* in_sizes, int n_in,
                              void* d_out, int out_size, void* d_ws, size_t ws_size,
                              hipStream_t stream) {
    const float* hv       = (const float*)d_in[0];
    const float* Wg       = (const float*)d_in[1];
    const float* bg       = (const float*)d_in[2];
    const float* Wp       = (const float*)d_in[3];
    const float* bp       = (const float*)d_in[4];
    const float* We       = (const float*)d_in[5];
    const float* be       = (const float*)d_in[6];
    const int*   seg_ids  = (const int*)d_in[7];
    const int*   last_idx = (const int*)d_in[8];
    const int*   a        = (const int*)d_in[9];
    float*       out      = (float*)d_out;

    int N = in_sizes[0] / D;
    int B = in_sizes[8];

    float* u  = (float*)d_ws;
    float* c  = (float*)((char*)d_ws + 512);
    float* s  = (float*)((char*)d_ws + 1024);
    float* pg = (float*)((char*)d_ws + 65536);

    // prep: 129 weight blocks + zero-s blocks + gather blocks (2 graphs each)
    int nzero   = (B / 4 + 63) / 64;
    int ngather = (B + 1) / 2;
    prep_kernel<<<129 + nzero + ngather, 64, 0, stream>>>(
        Wp, bp, We, hv, last_idx, u, c, s, pg, B, nzero);

    const int nblocks = 2048;                 // 8192 waves, 32 waves/CU
    int waves = nblocks * 256 / 64;
    int chunk = (N + waves - 1) / waves;
    chunk = (chunk + 1) & ~1;                 // even so both halves stay in-chunk
    node_kernel<<<nblocks, 256, 0, stream>>>(hv, Wg, bg, seg_ids, u, c, s, N, chunk);

    int fblocks = (B + 255) / 256;
    final_kernel<<<fblocks, 256, 0, stream>>>(s, pg, be, a, out, B);
}